// Round 1
// baseline (481.984 us; speedup 1.0000x reference)
//
#include <hip/hip_runtime.h>
#include <hip/hip_bf16.h>

typedef __attribute__((ext_vector_type(8))) short bf16x8;
typedef __attribute__((ext_vector_type(4))) float f32x4;
typedef unsigned short u16;

constexpr int B = 2, S = 2048, D = 2048, H = 16, HD = 128, ROT = 64;

// ---------------- cast f32 -> bf16 (vectorized) ----------------
__global__ void cast_kernel(const float* __restrict__ in, u16* __restrict__ out, int n4)
{
    int idx = blockIdx.x * blockDim.x + threadIdx.x;
    int stride = gridDim.x * blockDim.x;
    for (int i = idx; i < n4; i += stride) {
        float4 v = ((const float4*)in)[i];
        __hip_bfloat16 a = __float2bfloat16(v.x);
        __hip_bfloat16 b = __float2bfloat16(v.y);
        __hip_bfloat16 c = __float2bfloat16(v.z);
        __hip_bfloat16 d = __float2bfloat16(v.w);
        ushort4 o;
        o.x = *(u16*)&a; o.y = *(u16*)&b; o.z = *(u16*)&c; o.w = *(u16*)&d;
        ((ushort4*)out)[i] = o;
    }
}

// ---------------- prep: rope tables, keep, expo ----------------
__global__ void prep_kernel(const float* __restrict__ mask, const int* __restrict__ pos,
                            const float* __restrict__ ncst,
                            float* __restrict__ sinb, float* __restrict__ cosb,
                            float* __restrict__ keep, float* __restrict__ expo)
{
    int gid = blockIdx.x * blockDim.x + threadIdx.x;
    int total = B * S * 32;
    if (gid < total) {
        int j = gid & 31;
        int bs = gid >> 5;
        float p = (float)pos[bs];
        float f = powf(10000.f, -(float)j / 32.f);
        float ang = p * f;
        sinb[gid] = sinf(ang);
        cosb[gid] = cosf(ang);
        if (j == 0) keep[bs] = (mask[bs] == 0.f) ? 1.f : 0.f;
    }
    if (gid < H) expo[gid] = 1.f / (1.f + expf(-ncst[gid]));
}

// ---------------- counts: prefix sum of keep per batch ----------------
__global__ void counts_kernel(const float* __restrict__ keep, float* __restrict__ counts)
{
    __shared__ float ks[S];
    int b = blockIdx.x;
    for (int i = threadIdx.x; i < S; i += blockDim.x) ks[i] = keep[b * S + i];
    __syncthreads();
    for (int q = threadIdx.x; q < S; q += blockDim.x) {
        float c = 0.f;
        for (int k = 0; k <= q; ++k) c += ks[k];
        counts[b * S + q] = c;
    }
}

// ---------------- bf16 B^T GEMM: C[M][N] = A[M][K] * B[N][K]^T (f32 out) ----------------
__global__ __launch_bounds__(256, 2) void gemm_bt(
    const u16* __restrict__ A, const u16* __restrict__ Bm,
    float* __restrict__ C, int M, int N, int K)
{
    __shared__ u16 As[128][72];
    __shared__ u16 Bs[128][72];
    int tid = threadIdx.x;
    int lane = tid & 63, wid = tid >> 6;
    int wm = wid >> 1, wn = wid & 1;
    int bm = blockIdx.y, bn = blockIdx.x;
    const int l15 = lane & 15, l4 = lane >> 4;

    f32x4 acc[4][4] = {};

    for (int kt = 0; kt < K; kt += 64) {
#pragma unroll
        for (int i = 0; i < 4; ++i) {
            int q = tid + i * 256;
            int row = q >> 3, c8 = q & 7;
            uint4 av = *(const uint4*)(A + (size_t)(bm * 128 + row) * K + kt + c8 * 8);
            uint4 bv = *(const uint4*)(Bm + (size_t)(bn * 128 + row) * K + kt + c8 * 8);
            *(uint4*)(&As[row][c8 * 8]) = av;
            *(uint4*)(&Bs[row][c8 * 8]) = bv;
        }
        __syncthreads();
#pragma unroll
        for (int t = 0; t < 2; ++t) {
            bf16x8 a[4], b[4];
#pragma unroll
            for (int m = 0; m < 4; ++m)
                a[m] = *(const bf16x8*)(&As[wm * 64 + m * 16 + l15][t * 32 + l4 * 8]);
#pragma unroll
            for (int n = 0; n < 4; ++n)
                b[n] = *(const bf16x8*)(&Bs[wn * 64 + n * 16 + l15][t * 32 + l4 * 8]);
#pragma unroll
            for (int m = 0; m < 4; ++m)
#pragma unroll
                for (int n = 0; n < 4; ++n)
                    acc[m][n] = __builtin_amdgcn_mfma_f32_16x16x32_bf16(a[m], b[n], acc[m][n], 0, 0, 0);
        }
        __syncthreads();
    }
#pragma unroll
    for (int m = 0; m < 4; ++m) {
        int row = bm * 128 + wm * 64 + m * 16 + l4 * 4;
#pragma unroll
        for (int n = 0; n < 4; ++n) {
            int col = bn * 128 + wn * 64 + n * 16 + l15;
#pragma unroll
            for (int r = 0; r < 4; ++r)
                C[(size_t)(row + r) * N + col] = acc[m][n][r];
        }
    }
}

// ---------------- postproc q/k: RoPE + L2-normalize + keep -> bf16 (B,H,S,HD) ----------------
__global__ void postproc_qk(const float* __restrict__ tmp, u16* __restrict__ outp,
                            const float* __restrict__ sinb, const float* __restrict__ cosb,
                            const float* __restrict__ keep)
{
    int gw = (blockIdx.x * blockDim.x + threadIdx.x) >> 6;
    int lane = threadIdx.x & 63;
    if (gw >= B * S * H) return;
    int h = gw % H;
    int sb = gw / H;
    int s = sb % S;
    int b = sb / S;
    const float* rowp = tmp + (size_t)(b * S + s) * D + h * 128;
    float x0 = rowp[lane];
    float x1 = rowp[lane + 64];
    // RoPE on d<64 (x0). pairs (2i, 2i+1)
    int i = lane >> 1;
    float sn = sinb[(b * S + s) * 32 + i];
    float cs = cosb[(b * S + s) * 32 + i];
    float partner = __shfl_xor(x0, 1, 64);
    float r0 = (lane & 1) ? (x0 * cs + partner * sn) : (x0 * cs - partner * sn);
    x0 = r0;
    float ss = x0 * x0 + x1 * x1;
#pragma unroll
    for (int o = 1; o < 64; o <<= 1) ss += __shfl_xor(ss, o, 64);
    float nrm = sqrtf(ss);
    float scale = keep[b * S + s] / fmaxf(nrm, 1e-12f);
    __hip_bfloat16 h0 = __float2bfloat16(x0 * scale);
    __hip_bfloat16 h1 = __float2bfloat16(x1 * scale);
    size_t obase = ((size_t)(b * H + h) * S + s) * 128;
    outp[obase + lane] = *(u16*)&h0;
    outp[obase + lane + 64] = *(u16*)&h1;
}

// ---------------- postproc v: count-scale + keep -> bf16 transposed (B,H,HD,S) ----------------
__global__ void postproc_v(const float* __restrict__ tmp, u16* __restrict__ vT,
                           const float* __restrict__ keep, const float* __restrict__ counts,
                           const float* __restrict__ expo)
{
    int gw = (blockIdx.x * blockDim.x + threadIdx.x) >> 6;
    int lane = threadIdx.x & 63;
    if (gw >= B * S * H) return;
    int h = gw % H;
    int sb = gw / H;
    int s = sb % S;
    int b = sb / S;
    const float* rowp = tmp + (size_t)(b * S + s) * D + h * 128;
    float x0 = rowp[lane];
    float x1 = rowp[lane + 64];
    float cnt = counts[b * S + s];
    float e = expo[h];
    float div = fmaxf(powf(cnt, e), 1.0f);
    float scale = keep[b * S + s] / div;
    __hip_bfloat16 h0 = __float2bfloat16(x0 * scale);
    __hip_bfloat16 h1 = __float2bfloat16(x1 * scale);
    size_t obase = ((size_t)(b * H + h) * 128) * (size_t)S + s;
    vT[obase + (size_t)lane * S] = *(u16*)&h0;
    vT[obase + (size_t)(lane + 64) * S] = *(u16*)&h1;
}

// ---------------- causal linear attention (no softmax) ----------------
// out[q,d] = sum_{k<=q} (qn[q]·kn[k]) * v[k,d], per (b,h)
__global__ __launch_bounds__(256, 2) void attn_kernel(
    const u16* __restrict__ qn, const u16* __restrict__ kn,
    const u16* __restrict__ vT, u16* __restrict__ ao)
{
    __shared__ u16 KN[64][136];  // [k][d]
    __shared__ u16 VT[128][72];  // [d][k]
    __shared__ u16 SC[128][72];  // [q][k] scores as bf16
    int tid = threadIdx.x, lane = tid & 63, w = tid >> 6;
    int qt = blockIdx.x, bh = blockIdx.y;
    int b = bh >> 4, h = bh & 15;
    const int l15 = lane & 15, l4 = lane >> 4;
    size_t base = (size_t)bh * S * 128;
    size_t vbase = (size_t)bh * 128 * S;

    // hoist Q fragments (rows w*32 .. w*32+31 of this q-tile)
    bf16x8 qa[2][4];
#pragma unroll
    for (int m = 0; m < 2; ++m)
#pragma unroll
        for (int t = 0; t < 4; ++t) {
            int row = qt * 128 + w * 32 + m * 16 + l15;
            qa[m][t] = *(const bf16x8*)(qn + base + (size_t)row * 128 + t * 32 + l4 * 8);
        }

    f32x4 acc[2][8] = {};
    int nkt = 2 * qt + 2;
    for (int kt = 0; kt < nkt; ++kt) {
        // stage KN: 64 rows x 128 d
#pragma unroll
        for (int i = 0; i < 4; ++i) {
            int q = tid + i * 256;
            int r = q >> 4, c8 = q & 15;
            uint4 v = *(const uint4*)(kn + base + (size_t)(kt * 64 + r) * 128 + c8 * 8);
            *(uint4*)(&KN[r][c8 * 8]) = v;
        }
        // stage VT: 128 rows(d) x 64 k
#pragma unroll
        for (int i = 0; i < 4; ++i) {
            int q = tid + i * 256;
            int r = q >> 3, c8 = q & 7;
            uint4 v = *(const uint4*)(vT + vbase + (size_t)r * S + kt * 64 + c8 * 8);
            *(uint4*)(&VT[r][c8 * 8]) = v;
        }
        __syncthreads();
        // scores: S[q(32 rows of this wave)][k(64)] = Qn * Kn^T over d=128
        f32x4 sacc[2][4] = {};
#pragma unroll
        for (int t = 0; t < 4; ++t) {
            bf16x8 kb[4];
#pragma unroll
            for (int n = 0; n < 4; ++n)
                kb[n] = *(const bf16x8*)(&KN[n * 16 + l15][t * 32 + l4 * 8]);
#pragma unroll
            for (int m = 0; m < 2; ++m)
#pragma unroll
                for (int n = 0; n < 4; ++n)
                    sacc[m][n] = __builtin_amdgcn_mfma_f32_16x16x32_bf16(qa[m][t], kb[n], sacc[m][n], 0, 0, 0);
        }
        // mask + convert + store scores to LDS (same-wave region)
#pragma unroll
        for (int m = 0; m < 2; ++m)
#pragma unroll
            for (int n = 0; n < 4; ++n)
#pragma unroll
                for (int r = 0; r < 4; ++r) {
                    int rowl = w * 32 + m * 16 + l4 * 4 + r;
                    int coll = n * 16 + l15;
                    int qg = qt * 128 + rowl, kg = kt * 64 + coll;
                    float val = (kg <= qg) ? sacc[m][n][r] : 0.f;
                    __hip_bfloat16 hv = __float2bfloat16(val);
                    SC[rowl][coll] = *(u16*)&hv;
                }
        // out += SC * V  (A = SC[q][k], B^T = vT[d][k])
#pragma unroll
        for (int t = 0; t < 2; ++t) {
            bf16x8 sa[2], vb[8];
#pragma unroll
            for (int m = 0; m < 2; ++m)
                sa[m] = *(const bf16x8*)(&SC[w * 32 + m * 16 + l15][t * 32 + l4 * 8]);
#pragma unroll
            for (int n = 0; n < 8; ++n)
                vb[n] = *(const bf16x8*)(&VT[n * 16 + l15][t * 32 + l4 * 8]);
#pragma unroll
            for (int m = 0; m < 2; ++m)
#pragma unroll
                for (int n = 0; n < 8; ++n)
                    acc[m][n] = __builtin_amdgcn_mfma_f32_16x16x32_bf16(sa[m], vb[n], acc[m][n], 0, 0, 0);
        }
        __syncthreads();
    }
    // epilogue: write attn output at [b, s, h*128+d] as bf16
#pragma unroll
    for (int m = 0; m < 2; ++m)
#pragma unroll
        for (int n = 0; n < 8; ++n)
#pragma unroll
            for (int r = 0; r < 4; ++r) {
                int srow = qt * 128 + w * 32 + m * 16 + l4 * 4 + r;
                int d = n * 16 + l15;
                __hip_bfloat16 hv = __float2bfloat16(acc[m][n][r]);
                ao[(size_t)(b * S + srow) * D + h * 128 + d] = *(u16*)&hv;
            }
}

extern "C" void kernel_launch(void* const* d_in, const int* in_sizes, int n_in,
                              void* d_out, int out_size, void* d_ws, size_t ws_size,
                              hipStream_t stream)
{
    const float* hs = (const float*)d_in[0];
    const float* mask = (const float*)d_in[1];
    const int* pos = (const int*)d_in[2];
    const float* Wq = (const float*)d_in[3];
    const float* Wk = (const float*)d_in[4];
    const float* Wv = (const float*)d_in[5];
    const float* Wo = (const float*)d_in[6];
    const float* ncst = (const float*)d_in[7];
    float* out = (float*)d_out;

    char* ws = (char*)d_ws;
    size_t off = 0;
    auto alloc = [&](size_t bytes) {
        size_t o = off;
        off += (bytes + 255) & ~(size_t)255;
        return o;
    };
    u16* hs16 = (u16*)(ws + alloc((size_t)B * S * D * 2));
    u16* wq16 = (u16*)(ws + alloc((size_t)D * D * 2));
    u16* wk16 = (u16*)(ws + alloc((size_t)D * D * 2));
    u16* wv16 = (u16*)(ws + alloc((size_t)D * D * 2));
    u16* wo16 = (u16*)(ws + alloc((size_t)D * D * 2));
    float* tmp = (float*)(ws + alloc((size_t)B * S * D * 4));
    u16* qn16 = (u16*)(ws + alloc((size_t)B * S * D * 2));
    u16* kn16 = (u16*)(ws + alloc((size_t)B * S * D * 2));
    u16* vT16 = (u16*)(ws + alloc((size_t)B * S * D * 2));
    u16* ao16 = (u16*)(ws + alloc((size_t)B * S * D * 2));
    float* sinb = (float*)(ws + alloc((size_t)B * S * 32 * 4));
    float* cosb = (float*)(ws + alloc((size_t)B * S * 32 * 4));
    float* keep = (float*)(ws + alloc((size_t)B * S * 4));
    float* counts = (float*)(ws + alloc((size_t)B * S * 4));
    float* expo = (float*)(ws + alloc(64));

    // casts
    cast_kernel<<<2048, 256, 0, stream>>>(hs, hs16, B * S * D / 4);
    cast_kernel<<<1024, 256, 0, stream>>>(Wq, wq16, D * D / 4);
    cast_kernel<<<1024, 256, 0, stream>>>(Wk, wk16, D * D / 4);
    cast_kernel<<<1024, 256, 0, stream>>>(Wv, wv16, D * D / 4);
    cast_kernel<<<1024, 256, 0, stream>>>(Wo, wo16, D * D / 4);
    // prep
    prep_kernel<<<(B * S * 32 + 255) / 256, 256, 0, stream>>>(mask, pos, ncst, sinb, cosb, keep, expo);
    counts_kernel<<<B, 256, 0, stream>>>(keep, counts);

    dim3 gg(D / 128, (B * S) / 128);
    int pp_blocks = (B * S * H) / 4;

    // Q projection + postproc
    gemm_bt<<<gg, 256, 0, stream>>>(hs16, wq16, tmp, B * S, D, D);
    postproc_qk<<<pp_blocks, 256, 0, stream>>>(tmp, qn16, sinb, cosb, keep);
    // K projection + postproc
    gemm_bt<<<gg, 256, 0, stream>>>(hs16, wk16, tmp, B * S, D, D);
    postproc_qk<<<pp_blocks, 256, 0, stream>>>(tmp, kn16, sinb, cosb, keep);
    // V projection + postproc (transposed bf16 out)
    gemm_bt<<<gg, 256, 0, stream>>>(hs16, wv16, tmp, B * S, D, D);
    postproc_v<<<pp_blocks, 256, 0, stream>>>(tmp, vT16, keep, counts, expo);

    // attention
    dim3 ga(S / 128, B * H);
    attn_kernel<<<ga, 256, 0, stream>>>(qn16, kn16, vT16, ao16);

    // output projection -> f32 out
    gemm_bt<<<gg, 256, 0, stream>>>(ao16, wo16, out, B * S, D, D);
}

// Round 2
// 365.745 us; speedup vs baseline: 1.3178x; 1.3178x over previous
//
#include <hip/hip_runtime.h>
#include <hip/hip_bf16.h>

typedef __attribute__((ext_vector_type(8))) short bf16x8;
typedef __attribute__((ext_vector_type(4))) float f32x4;
typedef unsigned short u16;
typedef unsigned int u32;

constexpr int B = 2, S = 2048, D = 2048, H = 16, HD = 128, ROT = 64;
constexpr int NQKV = 3 * D;  // 6144

__device__ __forceinline__ void gload16(const u16* g, u16* l)
{
    __builtin_amdgcn_global_load_lds((const __attribute__((address_space(1))) void*)g,
                                     (__attribute__((address_space(3))) void*)l, 16, 0, 0);
}

__device__ __forceinline__ float bf2f(u32 lo16) { return __uint_as_float(lo16 << 16); }

// ---------------- cast f32 -> bf16 (vectorized) ----------------
__global__ void cast_kernel(const float* __restrict__ in, u16* __restrict__ out, int n4)
{
    int idx = blockIdx.x * blockDim.x + threadIdx.x;
    int stride = gridDim.x * blockDim.x;
    for (int i = idx; i < n4; i += stride) {
        float4 v = ((const float4*)in)[i];
        __hip_bfloat16 a = __float2bfloat16(v.x);
        __hip_bfloat16 b = __float2bfloat16(v.y);
        __hip_bfloat16 c = __float2bfloat16(v.z);
        __hip_bfloat16 d = __float2bfloat16(v.w);
        ushort4 o;
        o.x = *(u16*)&a; o.y = *(u16*)&b; o.z = *(u16*)&c; o.w = *(u16*)&d;
        ((ushort4*)out)[i] = o;
    }
}

// ---------------- prep: rope tables, keep, expo ----------------
__global__ void prep_kernel(const float* __restrict__ mask, const int* __restrict__ pos,
                            const float* __restrict__ ncst,
                            float* __restrict__ sinb, float* __restrict__ cosb,
                            float* __restrict__ keep, float* __restrict__ expo)
{
    int gid = blockIdx.x * blockDim.x + threadIdx.x;
    int total = B * S * 32;
    if (gid < total) {
        int j = gid & 31;
        int bs = gid >> 5;
        float p = (float)pos[bs];
        float f = powf(10000.f, -(float)j / 32.f);
        float ang = p * f;
        sinb[gid] = sinf(ang);
        cosb[gid] = cosf(ang);
        if (j == 0) keep[bs] = (mask[bs] == 0.f) ? 1.f : 0.f;
    }
    if (gid < H) expo[gid] = 1.f / (1.f + expf(-ncst[gid]));
}

// ---------------- counts: inclusive prefix sum of keep per batch ----------------
__global__ void counts_kernel(const float* __restrict__ keep, float* __restrict__ counts)
{
    __shared__ float part[256];
    int b = blockIdx.x, t = threadIdx.x;
    float v[8];
    float s = 0.f;
    const float* kp = keep + b * S + t * 8;
#pragma unroll
    for (int i = 0; i < 8; ++i) { s += kp[i]; v[i] = s; }
    part[t] = s;
    __syncthreads();
    float off = 0.f;
    for (int j = 0; j < t; ++j) off += part[j];
    float* cp = counts + b * S + t * 8;
#pragma unroll
    for (int i = 0; i < 8; ++i) cp[i] = off + v[i];
}

// ---------------- m97-style bf16 B^T GEMM: C[M][N] = A[M][K] * B[N][K]^T ----------------
// 128x128 tile, BK=64, global_load_lds w16, double-buffered linear LDS.
template <int BF16OUT>
__global__ __launch_bounds__(256) void gemm_bt(
    const u16* __restrict__ A, const u16* __restrict__ Bm,
    float* __restrict__ Cf, u16* __restrict__ Cb, int N, int K)
{
    __shared__ u16 As[2][128 * 64];
    __shared__ u16 Bs[2][128 * 64];
    int tid = threadIdx.x;
    int lane = tid & 63, w = tid >> 6;
    int wm = w >> 1, wn = w & 1;
    int bm = blockIdx.y, bn = blockIdx.x;
    const int l15 = lane & 15, l4 = lane >> 4;

    // staging: wave w owns rows [w*32, w*32+32), 4 issues of 8 rows x 64 cols
    int srow = w * 32 + (lane >> 3);
    int scol = (lane & 7) * 8;
    const u16* gA = A + (size_t)(bm * 128 + srow) * K + scol;
    const u16* gB = Bm + (size_t)(bn * 128 + srow) * K + scol;

    f32x4 acc[4][4] = {};
    int nk = K / 64;

    // prologue: stage tile 0 into buf 0
#pragma unroll
    for (int i = 0; i < 4; ++i) {
        gload16(gA + (size_t)i * 8 * K, &As[0][(w * 32 + i * 8) * 64]);
        gload16(gB + (size_t)i * 8 * K, &Bs[0][(w * 32 + i * 8) * 64]);
    }
    __syncthreads();

    int cur = 0;
    for (int t = 0; t < nk; ++t) {
        if (t + 1 < nk) {
            const u16* ga = gA + (size_t)(t + 1) * 64;
            const u16* gb = gB + (size_t)(t + 1) * 64;
#pragma unroll
            for (int i = 0; i < 4; ++i) {
                gload16(ga + (size_t)i * 8 * K, &As[cur ^ 1][(w * 32 + i * 8) * 64]);
                gload16(gb + (size_t)i * 8 * K, &Bs[cur ^ 1][(w * 32 + i * 8) * 64]);
            }
        }
#pragma unroll
        for (int tt = 0; tt < 2; ++tt) {
            bf16x8 a[4], b[4];
#pragma unroll
            for (int m = 0; m < 4; ++m)
                a[m] = *(const bf16x8*)(&As[cur][(wm * 64 + m * 16 + l15) * 64 + tt * 32 + l4 * 8]);
#pragma unroll
            for (int n = 0; n < 4; ++n)
                b[n] = *(const bf16x8*)(&Bs[cur][(wn * 64 + n * 16 + l15) * 64 + tt * 32 + l4 * 8]);
#pragma unroll
            for (int m = 0; m < 4; ++m)
#pragma unroll
                for (int n = 0; n < 4; ++n)
                    acc[m][n] = __builtin_amdgcn_mfma_f32_16x16x32_bf16(a[m], b[n], acc[m][n], 0, 0, 0);
        }
        __syncthreads();
        cur ^= 1;
    }

#pragma unroll
    for (int m = 0; m < 4; ++m) {
        int row = bm * 128 + wm * 64 + m * 16 + l4 * 4;
#pragma unroll
        for (int n = 0; n < 4; ++n) {
            int col = bn * 128 + wn * 64 + n * 16 + l15;
#pragma unroll
            for (int r = 0; r < 4; ++r) {
                if (BF16OUT) {
                    __hip_bfloat16 hv = __float2bfloat16(acc[m][n][r]);
                    Cb[(size_t)(row + r) * N + col] = *(u16*)&hv;
                } else {
                    Cf[(size_t)(row + r) * N + col] = acc[m][n][r];
                }
            }
        }
    }
}

// ---------------- fused postproc: RoPE + norm (q,k), count-scale (v) ----------------
// one wave per (b,s,h); reads bf16 QKV gemm output, writes qn/kn (B,H,S,HD) + vT (B,H,HD,S)
__global__ void postproc_all(const u16* __restrict__ tmpb,
                             u16* __restrict__ qn, u16* __restrict__ kn, u16* __restrict__ vT,
                             const float* __restrict__ sinb, const float* __restrict__ cosb,
                             const float* __restrict__ keep, const float* __restrict__ counts,
                             const float* __restrict__ expo)
{
    int gw = (blockIdx.x * blockDim.x + threadIdx.x) >> 6;
    int lane = threadIdx.x & 63;
    if (gw >= B * S * H) return;
    int h = gw % H;
    int sb = gw / H;
    int s = sb % S;
    int b = sb / S;
    const u16* rowp = tmpb + (size_t)(b * S + s) * NQKV;
    u32 qv = *(const u32*)(rowp + h * 128 + lane * 2);
    u32 kv = *(const u32*)(rowp + D + h * 128 + lane * 2);
    u32 vv = *(const u32*)(rowp + 2 * D + h * 128 + lane * 2);
    float q0 = bf2f(qv & 0xffff), q1 = bf2f(qv >> 16);
    float k0 = bf2f(kv & 0xffff), k1 = bf2f(kv >> 16);
    float v0 = bf2f(vv & 0xffff), v1 = bf2f(vv >> 16);
    if (lane < 32) {
        float sn = sinb[(b * S + s) * 32 + lane];
        float cs = cosb[(b * S + s) * 32 + lane];
        float nq0 = q0 * cs - q1 * sn, nq1 = q1 * cs + q0 * sn;
        float nk0 = k0 * cs - k1 * sn, nk1 = k1 * cs + k0 * sn;
        q0 = nq0; q1 = nq1; k0 = nk0; k1 = nk1;
    }
    float sq = q0 * q0 + q1 * q1;
    float sk = k0 * k0 + k1 * k1;
#pragma unroll
    for (int o = 1; o < 64; o <<= 1) {
        sq += __shfl_xor(sq, o, 64);
        sk += __shfl_xor(sk, o, 64);
    }
    float kf = keep[b * S + s];
    float scq = kf / fmaxf(sqrtf(sq), 1e-12f);
    float sck = kf / fmaxf(sqrtf(sk), 1e-12f);
    float cnt = counts[b * S + s];
    float e = expo[h];
    float scv = kf / fmaxf(powf(cnt, e), 1.0f);

    __hip_bfloat16 a0 = __float2bfloat16(q0 * scq), a1 = __float2bfloat16(q1 * scq);
    __hip_bfloat16 b0 = __float2bfloat16(k0 * sck), b1 = __float2bfloat16(k1 * sck);
    __hip_bfloat16 c0 = __float2bfloat16(v0 * scv), c1 = __float2bfloat16(v1 * scv);
    size_t obase = ((size_t)(b * H + h) * S + s) * 128 + lane * 2;
    *(u32*)(qn + obase) = (u32)*(u16*)&a0 | ((u32)*(u16*)&a1 << 16);
    *(u32*)(kn + obase) = (u32)*(u16*)&b0 | ((u32)*(u16*)&b1 << 16);
    size_t vbase = ((size_t)(b * H + h) * 128) * (size_t)S + s;
    vT[vbase + (size_t)(2 * lane) * S] = *(u16*)&c0;
    vT[vbase + (size_t)(2 * lane + 1) * S] = *(u16*)&c1;
}

// ---------------- causal linear attention (no softmax) ----------------
__global__ __launch_bounds__(256, 2) void attn_kernel(
    const u16* __restrict__ qn, const u16* __restrict__ kn,
    const u16* __restrict__ vT, u16* __restrict__ ao)
{
    __shared__ u16 KN[64][136];  // [k][d]
    __shared__ u16 VT[128][72];  // [d][k]
    __shared__ u16 SC[128][72];  // [q][k] scores as bf16
    int tid = threadIdx.x, lane = tid & 63, w = tid >> 6;
    int qt = blockIdx.x, bh = blockIdx.y;
    int b = bh >> 4, h = bh & 15;
    const int l15 = lane & 15, l4 = lane >> 4;
    size_t base = (size_t)bh * S * 128;
    size_t vbase = (size_t)bh * 128 * S;

    bf16x8 qa[2][4];
#pragma unroll
    for (int m = 0; m < 2; ++m)
#pragma unroll
        for (int t = 0; t < 4; ++t) {
            int row = qt * 128 + w * 32 + m * 16 + l15;
            qa[m][t] = *(const bf16x8*)(qn + base + (size_t)row * 128 + t * 32 + l4 * 8);
        }

    f32x4 acc[2][8] = {};
    int nkt = 2 * qt + 2;
    for (int kt = 0; kt < nkt; ++kt) {
#pragma unroll
        for (int i = 0; i < 4; ++i) {
            int q = tid + i * 256;
            int r = q >> 4, c8 = q & 15;
            uint4 v = *(const uint4*)(kn + base + (size_t)(kt * 64 + r) * 128 + c8 * 8);
            *(uint4*)(&KN[r][c8 * 8]) = v;
        }
#pragma unroll
        for (int i = 0; i < 4; ++i) {
            int q = tid + i * 256;
            int r = q >> 3, c8 = q & 7;
            uint4 v = *(const uint4*)(vT + vbase + (size_t)r * S + kt * 64 + c8 * 8);
            *(uint4*)(&VT[r][c8 * 8]) = v;
        }
        __syncthreads();
        f32x4 sacc[2][4] = {};
#pragma unroll
        for (int t = 0; t < 4; ++t) {
            bf16x8 kb[4];
#pragma unroll
            for (int n = 0; n < 4; ++n)
                kb[n] = *(const bf16x8*)(&KN[n * 16 + l15][t * 32 + l4 * 8]);
#pragma unroll
            for (int m = 0; m < 2; ++m)
#pragma unroll
                for (int n = 0; n < 4; ++n)
                    sacc[m][n] = __builtin_amdgcn_mfma_f32_16x16x32_bf16(qa[m][t], kb[n], sacc[m][n], 0, 0, 0);
        }
#pragma unroll
        for (int m = 0; m < 2; ++m)
#pragma unroll
            for (int n = 0; n < 4; ++n)
#pragma unroll
                for (int r = 0; r < 4; ++r) {
                    int rowl = w * 32 + m * 16 + l4 * 4 + r;
                    int coll = n * 16 + l15;
                    int qg = qt * 128 + rowl, kg = kt * 64 + coll;
                    float val = (kg <= qg) ? sacc[m][n][r] : 0.f;
                    __hip_bfloat16 hv = __float2bfloat16(val);
                    SC[rowl][coll] = *(u16*)&hv;
                }
#pragma unroll
        for (int t = 0; t < 2; ++t) {
            bf16x8 sa[2], vb[8];
#pragma unroll
            for (int m = 0; m < 2; ++m)
                sa[m] = *(const bf16x8*)(&SC[w * 32 + m * 16 + l15][t * 32 + l4 * 8]);
#pragma unroll
            for (int n = 0; n < 8; ++n)
                vb[n] = *(const bf16x8*)(&VT[n * 16 + l15][t * 32 + l4 * 8]);
#pragma unroll
            for (int m = 0; m < 2; ++m)
#pragma unroll
                for (int n = 0; n < 8; ++n)
                    acc[m][n] = __builtin_amdgcn_mfma_f32_16x16x32_bf16(sa[m], vb[n], acc[m][n], 0, 0, 0);
        }
        __syncthreads();
    }
#pragma unroll
    for (int m = 0; m < 2; ++m)
#pragma unroll
        for (int n = 0; n < 8; ++n)
#pragma unroll
            for (int r = 0; r < 4; ++r) {
                int srow = qt * 128 + w * 32 + m * 16 + l4 * 4 + r;
                int d = n * 16 + l15;
                __hip_bfloat16 hv = __float2bfloat16(acc[m][n][r]);
                ao[(size_t)(b * S + srow) * D + h * 128 + d] = *(u16*)&hv;
            }
}

extern "C" void kernel_launch(void* const* d_in, const int* in_sizes, int n_in,
                              void* d_out, int out_size, void* d_ws, size_t ws_size,
                              hipStream_t stream)
{
    const float* hs = (const float*)d_in[0];
    const float* mask = (const float*)d_in[1];
    const int* pos = (const int*)d_in[2];
    const float* Wq = (const float*)d_in[3];
    const float* Wk = (const float*)d_in[4];
    const float* Wv = (const float*)d_in[5];
    const float* Wo = (const float*)d_in[6];
    const float* ncst = (const float*)d_in[7];
    float* out = (float*)d_out;

    char* ws = (char*)d_ws;
    size_t off = 0;
    auto alloc = [&](size_t bytes) {
        size_t o = off;
        off += (bytes + 255) & ~(size_t)255;
        return o;
    };
    u16* hs16 = (u16*)(ws + alloc((size_t)B * S * D * 2));
    u16* wqkv16 = (u16*)(ws + alloc((size_t)NQKV * D * 2));
    u16* wo16 = (u16*)(ws + alloc((size_t)D * D * 2));
    u16* tmpb = (u16*)(ws + alloc((size_t)B * S * NQKV * 2));
    u16* qn16 = (u16*)(ws + alloc((size_t)B * S * D * 2));
    u16* kn16 = (u16*)(ws + alloc((size_t)B * S * D * 2));
    u16* vT16 = (u16*)(ws + alloc((size_t)B * S * D * 2));
    float* sinb = (float*)(ws + alloc((size_t)B * S * 32 * 4));
    float* cosb = (float*)(ws + alloc((size_t)B * S * 32 * 4));
    float* keep = (float*)(ws + alloc((size_t)B * S * 4));
    float* counts = (float*)(ws + alloc((size_t)B * S * 4));
    float* expo = (float*)(ws + alloc(64));
    u16* ao16 = tmpb;  // alias: tmpb no longer needed once attn starts

    // casts
    cast_kernel<<<2048, 256, 0, stream>>>(hs, hs16, B * S * D / 4);
    cast_kernel<<<1024, 256, 0, stream>>>(Wq, wqkv16, D * D / 4);
    cast_kernel<<<1024, 256, 0, stream>>>(Wk, wqkv16 + (size_t)D * D, D * D / 4);
    cast_kernel<<<1024, 256, 0, stream>>>(Wv, wqkv16 + (size_t)2 * D * D, D * D / 4);
    cast_kernel<<<1024, 256, 0, stream>>>(Wo, wo16, D * D / 4);
    // prep
    prep_kernel<<<(B * S * 32 + 255) / 256, 256, 0, stream>>>(mask, pos, ncst, sinb, cosb, keep, expo);
    counts_kernel<<<B, 256, 0, stream>>>(keep, counts);

    // fused QKV projection (bf16 out)
    dim3 gqkv(NQKV / 128, (B * S) / 128);
    gemm_bt<1><<<gqkv, 256, 0, stream>>>(hs16, wqkv16, nullptr, tmpb, NQKV, D);

    // postproc
    postproc_all<<<(B * S * H) / 4, 256, 0, stream>>>(tmpb, qn16, kn16, vT16, sinb, cosb, keep, counts, expo);

    // attention
    dim3 ga(S / 128, B * H);
    attn_kernel<<<ga, 256, 0, stream>>>(qn16, kn16, vT16, ao16);

    // output projection -> f32 out
    dim3 go(D / 128, (B * S) / 128);
    gemm_bt<0><<<go, 256, 0, stream>>>(ao16, wo16, out, nullptr, D, D);
}

// Round 3
// 315.880 us; speedup vs baseline: 1.5258x; 1.1579x over previous
//
#include <hip/hip_runtime.h>
#include <hip/hip_bf16.h>

typedef __attribute__((ext_vector_type(8))) short bf16x8;
typedef __attribute__((ext_vector_type(4))) float f32x4;
typedef unsigned short u16;
typedef unsigned int u32;

constexpr int B = 2, S = 2048, D = 2048, H = 16, HD = 128, ROT = 64;
constexpr int NQKV = 3 * D;  // 6144

__device__ __forceinline__ void gload16(const u16* g, u16* l)
{
    __builtin_amdgcn_global_load_lds((const __attribute__((address_space(1))) void*)g,
                                     (__attribute__((address_space(3))) void*)l, 16, 0, 0);
}

__device__ __forceinline__ float bf2f(u32 lo16) { return __uint_as_float(lo16 << 16); }

// ---------------- cast f32 -> bf16 (vectorized) ----------------
__global__ void cast_kernel(const float* __restrict__ in, u16* __restrict__ out, int n4)
{
    int idx = blockIdx.x * blockDim.x + threadIdx.x;
    int stride = gridDim.x * blockDim.x;
    for (int i = idx; i < n4; i += stride) {
        float4 v = ((const float4*)in)[i];
        __hip_bfloat16 a = __float2bfloat16(v.x);
        __hip_bfloat16 b = __float2bfloat16(v.y);
        __hip_bfloat16 c = __float2bfloat16(v.z);
        __hip_bfloat16 d = __float2bfloat16(v.w);
        ushort4 o;
        o.x = *(u16*)&a; o.y = *(u16*)&b; o.z = *(u16*)&c; o.w = *(u16*)&d;
        ((ushort4*)out)[i] = o;
    }
}

// ---------------- prep: rope tables, keep, expo ----------------
__global__ void prep_kernel(const float* __restrict__ mask, const int* __restrict__ pos,
                            const float* __restrict__ ncst,
                            float* __restrict__ sinb, float* __restrict__ cosb,
                            float* __restrict__ keep, float* __restrict__ expo)
{
    int gid = blockIdx.x * blockDim.x + threadIdx.x;
    int total = B * S * 32;
    if (gid < total) {
        int j = gid & 31;
        int bs = gid >> 5;
        float p = (float)pos[bs];
        float f = powf(10000.f, -(float)j / 32.f);
        float ang = p * f;
        sinb[gid] = sinf(ang);
        cosb[gid] = cosf(ang);
        if (j == 0) keep[bs] = (mask[bs] == 0.f) ? 1.f : 0.f;
    }
    if (gid < H) expo[gid] = 1.f / (1.f + expf(-ncst[gid]));
}

// ---------------- counts: inclusive prefix sum of keep per batch ----------------
__global__ void counts_kernel(const float* __restrict__ keep, float* __restrict__ counts)
{
    __shared__ float part[256];
    int b = blockIdx.x, t = threadIdx.x;
    float v[8];
    float s = 0.f;
    const float* kp = keep + b * S + t * 8;
#pragma unroll
    for (int i = 0; i < 8; ++i) { s += kp[i]; v[i] = s; }
    part[t] = s;
    __syncthreads();
    float off = 0.f;
    for (int j = 0; j < t; ++j) off += part[j];
    float* cp = counts + b * S + t * 8;
#pragma unroll
    for (int i = 0; i < 8; ++i) cp[i] = off + v[i];
}

// ---------------- m97-style bf16 B^T GEMM: C[M][N] = A[M][K] * B[N][K]^T ----------------
template <int BF16OUT>
__global__ __launch_bounds__(256) void gemm_bt(
    const u16* __restrict__ A, const u16* __restrict__ Bm,
    float* __restrict__ Cf, u16* __restrict__ Cb, int N, int K)
{
    __shared__ u16 As[2][128 * 64];
    __shared__ u16 Bs[2][128 * 64];
    int tid = threadIdx.x;
    int lane = tid & 63, w = tid >> 6;
    int wm = w >> 1, wn = w & 1;
    int bm = blockIdx.y, bn = blockIdx.x;
    const int l15 = lane & 15, l4 = lane >> 4;

    int srow = w * 32 + (lane >> 3);
    int scol = (lane & 7) * 8;
    const u16* gA = A + (size_t)(bm * 128 + srow) * K + scol;
    const u16* gB = Bm + (size_t)(bn * 128 + srow) * K + scol;

    f32x4 acc[4][4] = {};
    int nk = K / 64;

#pragma unroll
    for (int i = 0; i < 4; ++i) {
        gload16(gA + (size_t)i * 8 * K, &As[0][(w * 32 + i * 8) * 64]);
        gload16(gB + (size_t)i * 8 * K, &Bs[0][(w * 32 + i * 8) * 64]);
    }
    __syncthreads();

    int cur = 0;
    for (int t = 0; t < nk; ++t) {
        if (t + 1 < nk) {
            const u16* ga = gA + (size_t)(t + 1) * 64;
            const u16* gb = gB + (size_t)(t + 1) * 64;
#pragma unroll
            for (int i = 0; i < 4; ++i) {
                gload16(ga + (size_t)i * 8 * K, &As[cur ^ 1][(w * 32 + i * 8) * 64]);
                gload16(gb + (size_t)i * 8 * K, &Bs[cur ^ 1][(w * 32 + i * 8) * 64]);
            }
        }
#pragma unroll
        for (int tt = 0; tt < 2; ++tt) {
            bf16x8 a[4], b[4];
#pragma unroll
            for (int m = 0; m < 4; ++m)
                a[m] = *(const bf16x8*)(&As[cur][(wm * 64 + m * 16 + l15) * 64 + tt * 32 + l4 * 8]);
#pragma unroll
            for (int n = 0; n < 4; ++n)
                b[n] = *(const bf16x8*)(&Bs[cur][(wn * 64 + n * 16 + l15) * 64 + tt * 32 + l4 * 8]);
#pragma unroll
            for (int m = 0; m < 4; ++m)
#pragma unroll
                for (int n = 0; n < 4; ++n)
                    acc[m][n] = __builtin_amdgcn_mfma_f32_16x16x32_bf16(a[m], b[n], acc[m][n], 0, 0, 0);
        }
        __syncthreads();
        cur ^= 1;
    }

#pragma unroll
    for (int m = 0; m < 4; ++m) {
        int row = bm * 128 + wm * 64 + m * 16 + l4 * 4;
#pragma unroll
        for (int n = 0; n < 4; ++n) {
            int col = bn * 128 + wn * 64 + n * 16 + l15;
#pragma unroll
            for (int r = 0; r < 4; ++r) {
                if (BF16OUT) {
                    __hip_bfloat16 hv = __float2bfloat16(acc[m][n][r]);
                    Cb[(size_t)(row + r) * N + col] = *(u16*)&hv;
                } else {
                    Cf[(size_t)(row + r) * N + col] = acc[m][n][r];
                }
            }
        }
    }
}

// ---------------- fused postproc: RoPE + norm (q,k), count-scale (v) ----------------
__global__ void postproc_all(const u16* __restrict__ tmpb,
                             u16* __restrict__ qn, u16* __restrict__ kn, u16* __restrict__ vT,
                             const float* __restrict__ sinb, const float* __restrict__ cosb,
                             const float* __restrict__ keep, const float* __restrict__ counts,
                             const float* __restrict__ expo)
{
    int gw = (blockIdx.x * blockDim.x + threadIdx.x) >> 6;
    int lane = threadIdx.x & 63;
    if (gw >= B * S * H) return;
    int h = gw % H;
    int sb = gw / H;
    int s = sb % S;
    int b = sb / S;
    const u16* rowp = tmpb + (size_t)(b * S + s) * NQKV;
    u32 qv = *(const u32*)(rowp + h * 128 + lane * 2);
    u32 kv = *(const u32*)(rowp + D + h * 128 + lane * 2);
    u32 vv = *(const u32*)(rowp + 2 * D + h * 128 + lane * 2);
    float q0 = bf2f(qv & 0xffff), q1 = bf2f(qv >> 16);
    float k0 = bf2f(kv & 0xffff), k1 = bf2f(kv >> 16);
    float v0 = bf2f(vv & 0xffff), v1 = bf2f(vv >> 16);
    if (lane < 32) {
        float sn = sinb[(b * S + s) * 32 + lane];
        float cs = cosb[(b * S + s) * 32 + lane];
        float nq0 = q0 * cs - q1 * sn, nq1 = q1 * cs + q0 * sn;
        float nk0 = k0 * cs - k1 * sn, nk1 = k1 * cs + k0 * sn;
        q0 = nq0; q1 = nq1; k0 = nk0; k1 = nk1;
    }
    float sq = q0 * q0 + q1 * q1;
    float sk = k0 * k0 + k1 * k1;
#pragma unroll
    for (int o = 1; o < 64; o <<= 1) {
        sq += __shfl_xor(sq, o, 64);
        sk += __shfl_xor(sk, o, 64);
    }
    float kf = keep[b * S + s];
    float scq = kf / fmaxf(sqrtf(sq), 1e-12f);
    float sck = kf / fmaxf(sqrtf(sk), 1e-12f);
    float cnt = counts[b * S + s];
    float e = expo[h];
    float scv = kf / fmaxf(powf(cnt, e), 1.0f);

    __hip_bfloat16 a0 = __float2bfloat16(q0 * scq), a1 = __float2bfloat16(q1 * scq);
    __hip_bfloat16 b0 = __float2bfloat16(k0 * sck), b1 = __float2bfloat16(k1 * sck);
    __hip_bfloat16 c0 = __float2bfloat16(v0 * scv), c1 = __float2bfloat16(v1 * scv);
    size_t obase = ((size_t)(b * H + h) * S + s) * 128 + lane * 2;
    *(u32*)(qn + obase) = (u32)*(u16*)&a0 | ((u32)*(u16*)&a1 << 16);
    *(u32*)(kn + obase) = (u32)*(u16*)&b0 | ((u32)*(u16*)&b1 << 16);
    size_t vbase = ((size_t)(b * H + h) * 128) * (size_t)S + s;
    vT[vbase + (size_t)(2 * lane) * S] = *(u16*)&c0;
    vT[vbase + (size_t)(2 * lane + 1) * S] = *(u16*)&c1;
}

// ---------------- chunk state: T_c[d][d'] = sum_{k in chunk} v[k,d] * kn[k,d'] ----------------
__global__ __launch_bounds__(256) void chunk_state(
    const u16* __restrict__ kn, const u16* __restrict__ vT, u16* __restrict__ T16)
{
    __shared__ u16 As[128][72];  // vT rows d, 64 k-cols
    __shared__ u16 Bs[128][72];  // kn^T rows d', 64 k-cols (transposed during staging)
    int tid = threadIdx.x, lane = tid & 63, w = tid >> 6;
    int wm = w >> 1, wn = w & 1;
    int c = blockIdx.x, bh = blockIdx.y;
    const int l15 = lane & 15, l4 = lane >> 4;
    size_t vbase = (size_t)bh * 128 * S;
    size_t kbase = (size_t)bh * S * 128;
    f32x4 acc[4][4] = {};

    for (int t = 0; t < 2; ++t) {
#pragma unroll
        for (int i = 0; i < 4; ++i) {
            int q = tid + i * 256;
            int r = q >> 3, c8 = q & 7;
            uint4 v = *(const uint4*)(vT + vbase + (size_t)r * S + c * 128 + t * 64 + c8 * 8);
            *(uint4*)(&As[r][c8 * 8]) = v;
        }
#pragma unroll
        for (int i = 0; i < 4; ++i) {
            int q = tid + i * 256;
            int r = q >> 4, c16 = q & 15;
            uint4 v = *(const uint4*)(kn + kbase + (size_t)(c * 128 + t * 64 + r) * 128 + c16 * 8);
            const u16* pv = (const u16*)&v;
#pragma unroll
            for (int j = 0; j < 8; ++j) Bs[c16 * 8 + j][r] = pv[j];
        }
        __syncthreads();
#pragma unroll
        for (int tt = 0; tt < 2; ++tt) {
            bf16x8 a[4], b[4];
#pragma unroll
            for (int m = 0; m < 4; ++m)
                a[m] = *(const bf16x8*)(&As[wm * 64 + m * 16 + l15][tt * 32 + l4 * 8]);
#pragma unroll
            for (int n = 0; n < 4; ++n)
                b[n] = *(const bf16x8*)(&Bs[wn * 64 + n * 16 + l15][tt * 32 + l4 * 8]);
#pragma unroll
            for (int m = 0; m < 4; ++m)
#pragma unroll
                for (int n = 0; n < 4; ++n)
                    acc[m][n] = __builtin_amdgcn_mfma_f32_16x16x32_bf16(a[m], b[n], acc[m][n], 0, 0, 0);
        }
        __syncthreads();
    }
#pragma unroll
    for (int m = 0; m < 4; ++m) {
        int row = wm * 64 + m * 16 + l4 * 4;
#pragma unroll
        for (int n = 0; n < 4; ++n) {
            int col = wn * 64 + n * 16 + l15;
#pragma unroll
            for (int r = 0; r < 4; ++r) {
                __hip_bfloat16 hv = __float2bfloat16(acc[m][n][r]);
                T16[((size_t)(bh * 16 + c) * 128 + row + r) * 128 + col] = *(u16*)&hv;
            }
        }
    }
}

// ---------------- exclusive prefix over chunks: P_c = sum_{c'<c} T_c' ----------------
__global__ void prefix_state(const u16* __restrict__ T16, u16* __restrict__ P16)
{
    int g = blockIdx.x * blockDim.x + threadIdx.x;  // 65536 threads, 8 elems each
    int bh = g >> 11;
    int i8 = (g & 2047) * 8;
    const u16* tp = T16 + (size_t)bh * 16 * 16384 + i8;
    u16* pp = P16 + (size_t)bh * 16 * 16384 + i8;
    float run[8] = {};
    for (int c = 0; c < 16; ++c) {
        u16 ob[8];
#pragma unroll
        for (int j = 0; j < 8; ++j) { __hip_bfloat16 hv = __float2bfloat16(run[j]); ob[j] = *(u16*)&hv; }
        *(uint4*)(pp + (size_t)c * 16384) = *(uint4*)ob;
        uint4 tv = *(const uint4*)(tp + (size_t)c * 16384);
        const u16* tvp = (const u16*)&tv;
#pragma unroll
        for (int j = 0; j < 8; ++j) run[j] += bf2f(tvp[j]);
    }
}

// ---------------- chunked attention: out_c = qn_c . P_c + causal_intra ----------------
__global__ __launch_bounds__(256, 2) void attn2(
    const u16* __restrict__ qn, const u16* __restrict__ kn,
    const u16* __restrict__ vT, const u16* __restrict__ P16, u16* __restrict__ ao)
{
    __shared__ u16 KN[64][136];
    __shared__ u16 VT[128][72];
    __shared__ u16 SC[128][72];
    int tid = threadIdx.x, lane = tid & 63, w = tid >> 6;
    int c = blockIdx.x, bh = blockIdx.y;
    int b = bh >> 4, h = bh & 15;
    const int l15 = lane & 15, l4 = lane >> 4;
    size_t base = (size_t)bh * S * 128;
    size_t vbase = (size_t)bh * 128 * S;
    const u16* Pp = P16 + (size_t)(bh * 16 + c) * 16384;

    // hoist Q fragments (full K=128 of rows c*128 + w*32 .. +31)
    bf16x8 qa[2][4];
#pragma unroll
    for (int m = 0; m < 2; ++m)
#pragma unroll
        for (int t = 0; t < 4; ++t) {
            int row = c * 128 + w * 32 + m * 16 + l15;
            qa[m][t] = *(const bf16x8*)(qn + base + (size_t)row * 128 + t * 32 + l4 * 8);
        }

    f32x4 acc[2][8] = {};

    // ---- inter: out += qn_c . P_c  (P[d][d'], staged as B-operand over 2 d'-tiles) ----
#pragma unroll
    for (int pt = 0; pt < 2; ++pt) {
#pragma unroll
        for (int i = 0; i < 4; ++i) {
            int q = tid + i * 256;
            int r = q >> 3, c8 = q & 7;
            uint4 v = *(const uint4*)(Pp + (size_t)r * 128 + pt * 64 + c8 * 8);
            *(uint4*)(&VT[r][c8 * 8]) = v;
        }
        __syncthreads();
#pragma unroll
        for (int tt = 0; tt < 2; ++tt) {
            bf16x8 pb[8];
#pragma unroll
            for (int n = 0; n < 8; ++n)
                pb[n] = *(const bf16x8*)(&VT[n * 16 + l15][tt * 32 + l4 * 8]);
#pragma unroll
            for (int m = 0; m < 2; ++m)
#pragma unroll
                for (int n = 0; n < 8; ++n)
                    acc[m][n] = __builtin_amdgcn_mfma_f32_16x16x32_bf16(qa[m][pt * 2 + tt], pb[n], acc[m][n], 0, 0, 0);
        }
        __syncthreads();
    }

    // ---- intra: 2 causal k-tiles within the chunk ----
    for (int kt2 = 0; kt2 < 2; ++kt2) {
#pragma unroll
        for (int i = 0; i < 4; ++i) {
            int q = tid + i * 256;
            int r = q >> 4, c8 = q & 15;
            uint4 v = *(const uint4*)(kn + base + (size_t)(c * 128 + kt2 * 64 + r) * 128 + c8 * 8);
            *(uint4*)(&KN[r][c8 * 8]) = v;
        }
#pragma unroll
        for (int i = 0; i < 4; ++i) {
            int q = tid + i * 256;
            int r = q >> 3, c8 = q & 7;
            uint4 v = *(const uint4*)(vT + vbase + (size_t)r * S + c * 128 + kt2 * 64 + c8 * 8);
            *(uint4*)(&VT[r][c8 * 8]) = v;
        }
        __syncthreads();
        f32x4 sacc[2][4] = {};
#pragma unroll
        for (int t = 0; t < 4; ++t) {
            bf16x8 kb[4];
#pragma unroll
            for (int n = 0; n < 4; ++n)
                kb[n] = *(const bf16x8*)(&KN[n * 16 + l15][t * 32 + l4 * 8]);
#pragma unroll
            for (int m = 0; m < 2; ++m)
#pragma unroll
                for (int n = 0; n < 4; ++n)
                    sacc[m][n] = __builtin_amdgcn_mfma_f32_16x16x32_bf16(qa[m][t], kb[n], sacc[m][n], 0, 0, 0);
        }
#pragma unroll
        for (int m = 0; m < 2; ++m)
#pragma unroll
            for (int n = 0; n < 4; ++n)
#pragma unroll
                for (int r = 0; r < 4; ++r) {
                    int rowl = w * 32 + m * 16 + l4 * 4 + r;       // local q (0..127)
                    int coll = n * 16 + l15;                       // local col within tile
                    int kl = kt2 * 64 + coll;                      // local k (0..127)
                    float val = (kl <= rowl) ? sacc[m][n][r] : 0.f;
                    __hip_bfloat16 hv = __float2bfloat16(val);
                    SC[rowl][coll] = *(u16*)&hv;
                }
#pragma unroll
        for (int t = 0; t < 2; ++t) {
            bf16x8 sa[2], vb[8];
#pragma unroll
            for (int m = 0; m < 2; ++m)
                sa[m] = *(const bf16x8*)(&SC[w * 32 + m * 16 + l15][t * 32 + l4 * 8]);
#pragma unroll
            for (int n = 0; n < 8; ++n)
                vb[n] = *(const bf16x8*)(&VT[n * 16 + l15][t * 32 + l4 * 8]);
#pragma unroll
            for (int m = 0; m < 2; ++m)
#pragma unroll
                for (int n = 0; n < 8; ++n)
                    acc[m][n] = __builtin_amdgcn_mfma_f32_16x16x32_bf16(sa[m], vb[n], acc[m][n], 0, 0, 0);
        }
        __syncthreads();
    }

    // epilogue
#pragma unroll
    for (int m = 0; m < 2; ++m)
#pragma unroll
        for (int n = 0; n < 8; ++n)
#pragma unroll
            for (int r = 0; r < 4; ++r) {
                int srow = c * 128 + w * 32 + m * 16 + l4 * 4 + r;
                int d = n * 16 + l15;
                __hip_bfloat16 hv = __float2bfloat16(acc[m][n][r]);
                ao[(size_t)(b * S + srow) * D + h * 128 + d] = *(u16*)&hv;
            }
}

extern "C" void kernel_launch(void* const* d_in, const int* in_sizes, int n_in,
                              void* d_out, int out_size, void* d_ws, size_t ws_size,
                              hipStream_t stream)
{
    const float* hs = (const float*)d_in[0];
    const float* mask = (const float*)d_in[1];
    const int* pos = (const int*)d_in[2];
    const float* Wq = (const float*)d_in[3];
    const float* Wk = (const float*)d_in[4];
    const float* Wv = (const float*)d_in[5];
    const float* Wo = (const float*)d_in[6];
    const float* ncst = (const float*)d_in[7];
    float* out = (float*)d_out;

    char* ws = (char*)d_ws;
    size_t off = 0;
    auto alloc = [&](size_t bytes) {
        size_t o = off;
        off += (bytes + 255) & ~(size_t)255;
        return o;
    };
    u16* hs16 = (u16*)(ws + alloc((size_t)B * S * D * 2));
    u16* wqkv16 = (u16*)(ws + alloc((size_t)NQKV * D * 2));
    u16* wo16 = (u16*)(ws + alloc((size_t)D * D * 2));
    u16* tmpb = (u16*)(ws + alloc((size_t)B * S * NQKV * 2));
    u16* qn16 = (u16*)(ws + alloc((size_t)B * S * D * 2));
    u16* kn16 = (u16*)(ws + alloc((size_t)B * S * D * 2));
    u16* vT16 = (u16*)(ws + alloc((size_t)B * S * D * 2));
    float* sinb = (float*)(ws + alloc((size_t)B * S * 32 * 4));
    float* cosb = (float*)(ws + alloc((size_t)B * S * 32 * 4));
    float* keep = (float*)(ws + alloc((size_t)B * S * 4));
    float* counts = (float*)(ws + alloc((size_t)B * S * 4));
    float* expo = (float*)(ws + alloc(64));
    // carve ao/T/P out of tmpb (dead after postproc): 3 x 16.78MB = 50.33MB = sizeof(tmpb)
    u16* ao16 = tmpb;
    u16* T16 = tmpb + (size_t)8388608;
    u16* P16 = tmpb + (size_t)16777216;

    cast_kernel<<<2048, 256, 0, stream>>>(hs, hs16, B * S * D / 4);
    cast_kernel<<<1024, 256, 0, stream>>>(Wq, wqkv16, D * D / 4);
    cast_kernel<<<1024, 256, 0, stream>>>(Wk, wqkv16 + (size_t)D * D, D * D / 4);
    cast_kernel<<<1024, 256, 0, stream>>>(Wv, wqkv16 + (size_t)2 * D * D, D * D / 4);
    cast_kernel<<<1024, 256, 0, stream>>>(Wo, wo16, D * D / 4);
    prep_kernel<<<(B * S * 32 + 255) / 256, 256, 0, stream>>>(mask, pos, ncst, sinb, cosb, keep, expo);
    counts_kernel<<<B, 256, 0, stream>>>(keep, counts);

    // fused QKV projection (bf16 out)
    dim3 gqkv(NQKV / 128, (B * S) / 128);
    gemm_bt<1><<<gqkv, 256, 0, stream>>>(hs16, wqkv16, nullptr, tmpb, NQKV, D);

    postproc_all<<<(B * S * H) / 4, 256, 0, stream>>>(tmpb, qn16, kn16, vT16, sinb, cosb, keep, counts, expo);

    // chunked linear attention
    dim3 gc(S / 128, B * H);
    chunk_state<<<gc, 256, 0, stream>>>(kn16, vT16, T16);
    prefix_state<<<256, 256, 0, stream>>>(T16, P16);
    attn2<<<gc, 256, 0, stream>>>(qn16, kn16, vT16, P16, ao16);

    // output projection -> f32 out
    dim3 go(D / 128, (B * S) / 128);
    gemm_bt<0><<<go, 256, 0, stream>>>(ao16, wo16, out, nullptr, D, D);
}